// Round 1
// baseline (245.719 us; speedup 1.0000x reference)
//
#include <hip/hip_runtime.h>
#include <stdint.h>

#define NTOT 8192
#define BHALF 4096
#define DZ 512
#define DC 128
#define CS 4
#define COLS_PER_BLK (NTOT / CS)   // 2048
#define TEMPV 0.5f

typedef __attribute__((ext_vector_type(8))) short short8;     // 8 bf16 (4 VGPRs)
typedef __attribute__((ext_vector_type(4))) float f32x4;
typedef __attribute__((ext_vector_type(4))) float floatx4;
typedef __attribute__((ext_vector_type(4))) unsigned short u16x4;
typedef unsigned short u16;

__device__ __forceinline__ u16 f2bf(float x) {
  uint32_t u = __builtin_bit_cast(uint32_t, x);
  u += 0x7fffu + ((u >> 16) & 1u);   // RNE
  return (u16)(u >> 16);
}

// ---------------- convert: fp32 -> bf16 (z = [z_i;z_j], c = [c_i;c_j]) ----------------
__global__ void convert_kernel(const float* __restrict__ z_i, const float* __restrict__ z_j,
                               const float* __restrict__ c_i, const float* __restrict__ c_j,
                               u16* __restrict__ zb, u16* __restrict__ cb) {
  const int NZ4 = NTOT * DZ / 4;
  const int NC4 = NTOT * DC / 4;
  int stride = gridDim.x * blockDim.x;
  for (int i = blockIdx.x * blockDim.x + threadIdx.x; i < NZ4 + NC4; i += stride) {
    if (i < NZ4) {
      int flat = i * 4;
      int r = flat >> 9, d = flat & (DZ - 1);
      const float* src = (r < BHALF) ? (z_i + (size_t)r * DZ + d)
                                     : (z_j + (size_t)(r - BHALF) * DZ + d);
      floatx4 v = *(const floatx4*)src;
      u16x4 o;
      o[0] = f2bf(v[0]); o[1] = f2bf(v[1]); o[2] = f2bf(v[2]); o[3] = f2bf(v[3]);
      *(u16x4*)(zb + flat) = o;
    } else {
      int flat = (i - NZ4) * 4;
      int r = flat >> 7, d = flat & (DC - 1);
      const float* src = (r < BHALF) ? (c_i + (size_t)r * DC + d)
                                     : (c_j + (size_t)(r - BHALF) * DC + d);
      floatx4 v = *(const floatx4*)src;
      u16x4 o;
      o[0] = f2bf(v[0]); o[1] = f2bf(v[1]); o[2] = f2bf(v[2]); o[3] = f2bf(v[3]);
      *(u16x4*)(cb + flat) = o;
    }
  }
}

// ---------------- fused flash-style lse kernel ----------------
// block: 4 waves x 16 rows = 64 rows, columns [cs*2048, cs*2048+2048), 16 cols/iter.
// LDS tile layout: 16B chunks, chunk(n,k16) stored at index n*CHUNKS_PER_ROW + (k16 ^ (n&7))
// (XOR swizzle -> 2-way-max bank aliasing on ds_read_b128, compatible with global_load_lds)
__launch_bounds__(256, 2)
__global__ void fused_kernel(const u16* __restrict__ zb, const u16* __restrict__ cb,
                             float* __restrict__ lse_part, float* __restrict__ posArr) {
  __shared__ __align__(16) u16 zT[16 * DZ];  // 16 KB
  __shared__ __align__(16) u16 cT[16 * DC];  // 4 KB

  const int tid  = threadIdx.x;
  const int w    = tid >> 6;
  const int lane = tid & 63;
  const int q    = lane >> 4;   // quad id 0..3
  const int n    = lane & 15;   // col (B n / A m / C col) index

  const int rb = blockIdx.x >> 2;
  const int cs = blockIdx.x & 3;
  const int row_w    = rb * 64 + w * 16;          // this wave's 16 rows
  const int col_base = cs * COLS_PER_BLK;

  // A fragments in registers: lane holds A[m=n][k=q*8+j]
  short8 a_z[16];
  short8 a_c[4];
  {
    const int m_row = row_w + n;
    const u16* pz = zb + (size_t)m_row * DZ + q * 8;
#pragma unroll
    for (int kk = 0; kk < 16; ++kk) a_z[kk] = *(const short8*)(pz + kk * 32);
    const u16* pc = cb + (size_t)m_row * DC + q * 8;
#pragma unroll
    for (int kk = 0; kk < 4; ++kk) a_c[kk] = *(const short8*)(pc + kk * 32);
  }

  float mrow[4], lrow[4];
#pragma unroll
  for (int r = 0; r < 4; ++r) { mrow[r] = -3.0e38f; lrow[r] = 0.0f; }

  const int gr_base = row_w + q * 4;   // C/D: row = q*4 + reg

  for (int it = 0; it < COLS_PER_BLK / 16; ++it) {
    const int col0 = col_base + it * 16;
    __syncthreads();   // previous iteration's LDS reads done

    // stage z tile: 1024 chunks of 16B, 4 calls/wave
#pragma unroll
    for (int c4 = 0; c4 < 4; ++c4) {
      int chunk = c4 * 256 + w * 64 + lane;
      int rn  = chunk >> 6;
      int k16 = (chunk & 63) ^ (rn & 7);
      const u16* src = zb + (size_t)(col0 + rn) * DZ + k16 * 8;
      u16* dst = &zT[(c4 * 256 + w * 64) * 8];   // wave-uniform base, lane*16 implicit
      __builtin_amdgcn_global_load_lds((const __attribute__((address_space(1))) void*)src,
                                       (__attribute__((address_space(3))) void*)dst, 16, 0, 0);
    }
    // stage c tile: 256 chunks, 1 call/wave
    {
      int chunk = w * 64 + lane;
      int rn  = chunk >> 4;
      int k16 = (chunk & 15) ^ (rn & 7);
      const u16* src = cb + (size_t)(col0 + rn) * DC + k16 * 8;
      u16* dst = &cT[(w * 64) * 8];
      __builtin_amdgcn_global_load_lds((const __attribute__((address_space(1))) void*)src,
                                       (__attribute__((address_space(3))) void*)dst, 16, 0, 0);
    }
    __syncthreads();   // drains vmcnt(0) before barrier -> staged data visible

    f32x4 accz = {0.f, 0.f, 0.f, 0.f};
    f32x4 accc = {0.f, 0.f, 0.f, 0.f};
#pragma unroll
    for (int kk = 0; kk < 4; ++kk) {
      const short8 b = *(const short8*)&cT[(n * 16 + (((kk * 4) + q) ^ (n & 7))) * 8];
      accc = __builtin_amdgcn_mfma_f32_16x16x32_bf16(a_c[kk], b, accc, 0, 0, 0);
    }
#pragma unroll
    for (int kk = 0; kk < 16; ++kk) {
      const short8 b = *(const short8*)&zT[(n * 64 + (((kk * 4) + q) ^ (n & 7))) * 8];
      accz = __builtin_amdgcn_mfma_f32_16x16x32_bf16(a_z[kk], b, accz, 0, 0, 0);
    }

    const int gc = col0 + n;   // C/D: col = lane&15
#pragma unroll
    for (int r = 0; r < 4; ++r) {
      const int gr = gr_base + r;
      float tv = fmaxf(accc[r], TEMPV);
      const bool isPair = (gc == (gr ^ BHALF));   // (i+B)%N == i^B for pow2
      const bool isDiag = (gc == gr);
      if (isPair) tv = TEMPV;
      float s = accz[r] / tv;
      if (isPair) posArr[gr] = s;                 // exactly one writer per row
      float smax = isDiag ? -3.0e38f : s;
      float mn = fmaxf(mrow[r], smax);
      float e  = isDiag ? 0.0f : __expf(s - mn);
      lrow[r] = lrow[r] * __expf(mrow[r] - mn) + e;
      mrow[r] = mn;
    }
  }

  // merge the 16 column-lanes (online-softmax pairwise merge), write partial lse
#pragma unroll
  for (int r = 0; r < 4; ++r) {
    float mm = mrow[r], ll = lrow[r];
#pragma unroll
    for (int off = 1; off < 16; off <<= 1) {
      float m2 = __shfl_xor(mm, off);
      float l2 = __shfl_xor(ll, off);
      float mx = fmaxf(mm, m2);
      ll = ll * __expf(mm - mx) + l2 * __expf(m2 - mx);
      mm = mx;
    }
    if (n == 0) lse_part[(size_t)cs * NTOT + gr_base + r] = mm + __logf(ll);
  }
}

// ---------------- finalize: merge 4 column-split partial lse's, reduce ----------------
__global__ void finalize_kernel(const float* __restrict__ lse_part,
                                const float* __restrict__ posArr,
                                float* __restrict__ out) {
  __shared__ float red[1024];
  float acc = 0.0f;
  for (int row = threadIdx.x; row < NTOT; row += 1024) {
    float p0 = lse_part[row];
    float p1 = lse_part[NTOT + row];
    float p2 = lse_part[2 * NTOT + row];
    float p3 = lse_part[3 * NTOT + row];
    float M = fmaxf(fmaxf(p0, p1), fmaxf(p2, p3));
    float sum = __expf(p0 - M) + __expf(p1 - M) + __expf(p2 - M) + __expf(p3 - M);
    acc += (M + __logf(sum)) - posArr[row];
  }
  red[threadIdx.x] = acc;
  __syncthreads();
  for (int s = 512; s > 0; s >>= 1) {
    if ((int)threadIdx.x < s) red[threadIdx.x] += red[threadIdx.x + s];
    __syncthreads();
  }
  if (threadIdx.x == 0) out[0] = red[0] * (1.0f / NTOT);
}

extern "C" void kernel_launch(void* const* d_in, const int* in_sizes, int n_in,
                              void* d_out, int out_size, void* d_ws, size_t ws_size,
                              hipStream_t stream) {
  const float* z_i = (const float*)d_in[0];
  const float* z_j = (const float*)d_in[1];
  const float* c_i = (const float*)d_in[2];
  const float* c_j = (const float*)d_in[3];

  u16* zb = (u16*)d_ws;                              // 8192*512 bf16 = 8 MB
  u16* cb = zb + (size_t)NTOT * DZ;                  // 8192*128 bf16 = 2 MB
  float* lse_part = (float*)(cb + (size_t)NTOT * DC); // 4*8192 f32
  float* posArr   = lse_part + (size_t)CS * NTOT;     // 8192 f32

  convert_kernel<<<2560, 256, 0, stream>>>(z_i, z_j, c_i, c_j, zb, cb);
  fused_kernel<<<512, 256, 0, stream>>>(zb, cb, lse_part, posArr);
  finalize_kernel<<<1, 1024, 0, stream>>>(lse_part, posArr, (float*)d_out);
}